// Round 1
// baseline (5778.979 us; speedup 1.0000x reference)
//
#include <hip/hip_runtime.h>

#define BB 64
#define TT 4096
#define IN0 32
#define HH 128
#define G3 384
#define NOUT 32
#define CHX 16

typedef _Float16 h2 __attribute__((ext_vector_type(2)));
typedef _Float16 h8 __attribute__((ext_vector_type(8)));
union H8 { h8 v; h2 p[4]; };

// Single-WG fused pipeline: both GRU layers + fc in one workgroup per batch elem.
// All inter-layer handoff stays in LDS (no ring, no y0, no flags).
struct SM {
    float g0h[G3];           // layer-0 W_hh·h sums (bias folded)
    float g0i[G3];           // layer-0 W_ih·x sums (bias folded)
    float g1h[G3];           // layer-1 W_hh·h sums
    float g1i[G3];           // layer-1 W_ih·h0 sums
    float hs0[2][HH];        // h0 fp32 (for z*h term)
    float hs1[2][HH];        // h1 fp32 (also feeds fc)
    _Float16 hf0[2][HH];     // h0 f16 (matvec operand; = y0[t])
    _Float16 hf1[2][HH];     // h1 f16
    _Float16 xh[2][CHX][IN0];// x staged f16, 16-step chunks, double buffered
    float fcw[NOUT * 129];   // stride 129: conflict-free fc weight reads
    float fcb[NOUT];
    float pfc[NOUT * 9];     // fc partials (8-way K-split)
};

__device__ __forceinline__ float fast_sigmoid(float x) {
    x = fminf(fmaxf(x, -30.f), 30.f);
    float e = __expf(-x);
    return __builtin_amdgcn_rcpf(1.f + e);
}
__device__ __forceinline__ float fast_tanh(float x) {
    x = fminf(fmaxf(x, -15.f), 15.f);
    float e = __expf(-2.f * x);
    return (1.f - e) * __builtin_amdgcn_rcpf(1.f + e);
}
__device__ __forceinline__ float fdot2(h2 a, h2 b, float c) {
#if __has_builtin(__builtin_amdgcn_fdot2)
    return __builtin_amdgcn_fdot2(a, b, c, false);   // v_dot2_f32_f16, fp32 accum
#else
    return fmaf((float)a.x, (float)b.x, fmaf((float)a.y, (float)b.y, c));
#endif
}
__device__ __forceinline__ h2 cvt2(float a, float b) {
    h2 r; r.x = (_Float16)a; r.y = (_Float16)b; return r;
}
// quad-lane butterfly via DPP (VALU pipe, no LDS traffic)
__device__ __forceinline__ float qxor1(float v) {   // lanes 0123 -> 1032
    return __int_as_float(__builtin_amdgcn_mov_dpp(__float_as_int(v), 0xB1, 0xF, 0xF, true));
}
__device__ __forceinline__ float qxor2(float v) {   // lanes 0123 -> 2301
    return __int_as_float(__builtin_amdgcn_mov_dpp(__float_as_int(v), 0x4E, 0xF, 0xF, true));
}

extern "C" __global__ void __launch_bounds__(768, 3)
gru_fused_kernel(
    const float* __restrict__ x,
    const float* __restrict__ W_ih0, const float* __restrict__ W_hh0,
    const float* __restrict__ b_ih0, const float* __restrict__ b_hh0,
    const float* __restrict__ W_ih1, const float* __restrict__ W_hh1,
    const float* __restrict__ b_ih1, const float* __restrict__ b_hh1,
    const float* __restrict__ fc_w, const float* __restrict__ fc_b,
    float* __restrict__ out, float* __restrict__ hstack)
{
    __shared__ SM sm;
    const int b = blockIdx.x;
    const int tid = threadIdx.x;
    // thread = row-pair x K-quarter; kq in adjacent lanes -> DPP quad reduce
    const int rp = tid >> 2, kq = tid & 3;
    const int r0 = 2 * rp, r1 = r0 + 1;
    const float* xb = x + (size_t)b * TT * IN0;
    float* outb = out + (size_t)b * TT * NOUT;

    // register-resident f16 weights: 2 rows x 32-K slice of each matrix
    h2 wh0[32], wh1[32], wi1[32], wi0[8];
    #pragma unroll
    for (int i = 0; i < 16; ++i) {
        float2 f;
        f = *(const float2*)&W_hh0[r0*HH + kq*32 + 2*i]; wh0[i]    = cvt2(f.x, f.y);
        f = *(const float2*)&W_hh0[r1*HH + kq*32 + 2*i]; wh0[16+i] = cvt2(f.x, f.y);
        f = *(const float2*)&W_hh1[r0*HH + kq*32 + 2*i]; wh1[i]    = cvt2(f.x, f.y);
        f = *(const float2*)&W_hh1[r1*HH + kq*32 + 2*i]; wh1[16+i] = cvt2(f.x, f.y);
        f = *(const float2*)&W_ih1[r0*HH + kq*32 + 2*i]; wi1[i]    = cvt2(f.x, f.y);
        f = *(const float2*)&W_ih1[r1*HH + kq*32 + 2*i]; wi1[16+i] = cvt2(f.x, f.y);
    }
    #pragma unroll
    for (int i = 0; i < 4; ++i) {
        float2 f;
        f = *(const float2*)&W_ih0[r0*IN0 + kq*8 + 2*i]; wi0[i]   = cvt2(f.x, f.y);
        f = *(const float2*)&W_ih0[r1*IN0 + kq*8 + 2*i]; wi0[4+i] = cvt2(f.x, f.y);
    }
    // biases folded into kq==0 lane's accumulator init
    const bool lead = (kq == 0);
    const float bh0a = lead ? b_hh0[r0] : 0.f, bh0b = lead ? b_hh0[r1] : 0.f;
    const float bh1a = lead ? b_hh1[r0] : 0.f, bh1b = lead ? b_hh1[r1] : 0.f;
    const float bi1a = lead ? b_ih1[r0] : 0.f, bi1b = lead ? b_ih1[r1] : 0.f;
    const float bi0a = lead ? b_ih0[r0] : 0.f, bi0b = lead ? b_ih0[r1] : 0.f;

    if (tid < HH) {
        sm.hs0[0][tid] = 0.f; sm.hs0[1][tid] = 0.f;
        sm.hs1[0][tid] = 0.f; sm.hs1[1][tid] = 0.f;
        sm.hf0[0][tid] = (_Float16)0.f; sm.hf0[1][tid] = (_Float16)0.f;
        sm.hf1[0][tid] = (_Float16)0.f; sm.hf1[1][tid] = (_Float16)0.f;
    }
    for (int i = tid; i < NOUT * HH; i += 768)
        sm.fcw[(i >> 7) * 129 + (i & 127)] = fc_w[i];
    if (tid < NOUT) sm.fcb[tid] = fc_b[tid];
    if (tid >= 640) {                          // stage x chunk 0 (steps 0..15)
        int i = tid - 640;
        float4 f = ((const float4*)xb)[i];
        ((h2*)&sm.xh[0][0][0])[2*i]   = cvt2(f.x, f.y);
        ((h2*)&sm.xh[0][0][0])[2*i+1] = cvt2(f.z, f.w);
    }
    __syncthreads();

    // schedule: step s: L0 computes h0[s] (s<T); L1 computes h1[s-1] (1<=s<=T);
    // fc partial on h1[s-2] (2<=s<=T+1); fc reduce -> out[s-3] (3<=s<=T+2).
    int cur = 0;
    float4 pf;
    for (int s = 0; s <= TT + 2; ++s) {
        const int nxt = cur ^ 1;
        // -------- phase 1: matvecs + fc reduce + x prefetch issue --------
        if (tid >= 640 && (s & (CHX - 1)) == 0 && s + CHX < TT) {
            pf = ((const float4*)(xb + (size_t)(s + CHX) * IN0))[tid - 640];
        }
        if (s <= TT) {
            const h8* hv0 = (const h8*)&sm.hf0[cur][kq * 32];
            const h8* hv1 = (const h8*)&sm.hf1[cur][kq * 32];
            float g0h_0 = bh0a, g0h_1 = bh0b;
            float g1h_0 = bh1a, g1h_1 = bh1b;
            float g1i_0 = bi1a, g1i_1 = bi1b;
            float g0i_0 = bi0a, g0i_1 = bi0b;
            #pragma unroll
            for (int i = 0; i < 4; ++i) {
                H8 h0c; h0c.v = hv0[i];          // h0 read serves gh0 AND gi1
                H8 h1c; h1c.v = hv1[i];
                #pragma unroll
                for (int j = 0; j < 4; ++j) {
                    const int w = 4 * i + j;
                    g0h_0 = fdot2(wh0[w],      h0c.p[j], g0h_0);
                    g0h_1 = fdot2(wh0[16 + w], h0c.p[j], g0h_1);
                    g1i_0 = fdot2(wi1[w],      h0c.p[j], g1i_0);
                    g1i_1 = fdot2(wi1[16 + w], h0c.p[j], g1i_1);
                    g1h_0 = fdot2(wh1[w],      h1c.p[j], g1h_0);
                    g1h_1 = fdot2(wh1[16 + w], h1c.p[j], g1h_1);
                }
            }
            {
                H8 xc; xc.v = *(const h8*)&sm.xh[(s >> 4) & 1][s & 15][kq * 8];
                #pragma unroll
                for (int j = 0; j < 4; ++j) {
                    g0i_0 = fdot2(wi0[j],     xc.p[j], g0i_0);
                    g0i_1 = fdot2(wi0[4 + j], xc.p[j], g0i_1);
                }
            }
            // quad butterfly: all 4 kq lanes end with full row sums
            g0h_0 += qxor1(g0h_0); g0h_0 += qxor2(g0h_0);
            g0h_1 += qxor1(g0h_1); g0h_1 += qxor2(g0h_1);
            g1h_0 += qxor1(g1h_0); g1h_0 += qxor2(g1h_0);
            g1h_1 += qxor1(g1h_1); g1h_1 += qxor2(g1h_1);
            g1i_0 += qxor1(g1i_0); g1i_0 += qxor2(g1i_0);
            g1i_1 += qxor1(g1i_1); g1i_1 += qxor2(g1i_1);
            g0i_0 += qxor1(g0i_0); g0i_0 += qxor2(g0i_0);
            g0i_1 += qxor1(g0i_1); g0i_1 += qxor2(g0i_1);
            // one float2 store per lane; banks conflict-free
            if (kq == 0)      { *(float2*)&sm.g0h[r0] = make_float2(g0h_0, g0h_1); }
            else if (kq == 1) { *(float2*)&sm.g1h[r0] = make_float2(g1h_0, g1h_1); }
            else if (kq == 2) { *(float2*)&sm.g1i[r0] = make_float2(g1i_0, g1i_1); }
            else              { *(float2*)&sm.g0i[r0] = make_float2(g0i_0, g0i_1); }
        }
        if (tid >= 704 && tid < 736 && s >= 3) {   // fc reduce -> out[s-3]
            const int o = tid - 704;
            float sum = sm.fcb[o];
            #pragma unroll
            for (int j2 = 0; j2 < 8; ++j2) sum += sm.pfc[o * 9 + j2];
            outb[(size_t)(s - 3) * NOUT + o] = sum;
        }
        __syncthreads();
        // -------- phase 2: activations + fc partials + x stage write --------
        if (tid < HH) {
            if (s < TT) {                           // layer-0 activation
                const int j = tid;
                float rg = fast_sigmoid(sm.g0i[j] + sm.g0h[j]);
                float zg = fast_sigmoid(sm.g0i[j + HH] + sm.g0h[j + HH]);
                float ng = fast_tanh(sm.g0i[j + 2 * HH] + rg * sm.g0h[j + 2 * HH]);
                float hn = (1.f - zg) * ng + zg * sm.hs0[cur][j];
                sm.hs0[nxt][j] = hn;
                sm.hf0[nxt][j] = (_Float16)hn;
                if (s == TT - 1) hstack[(size_t)b * HH + j] = hn;
            }
        } else if (tid < 2 * HH) {
            if (s >= 1 && s <= TT) {                // layer-1 activation (h1[s-1])
                const int j = tid - HH;
                float rg = fast_sigmoid(sm.g1i[j] + sm.g1h[j]);
                float zg = fast_sigmoid(sm.g1i[j + HH] + sm.g1h[j + HH]);
                float ng = fast_tanh(sm.g1i[j + 2 * HH] + rg * sm.g1h[j + 2 * HH]);
                float hn = (1.f - zg) * ng + zg * sm.hs1[cur][j];
                sm.hs1[nxt][j] = hn;
                sm.hf1[nxt][j] = (_Float16)hn;
                if (s == TT) hstack[(size_t)(BB + b) * HH + j] = hn;
            }
        } else if (tid >= 384 && tid < 640) {
            if (s >= 2 && s <= TT + 1) {            // fc partials on h1[s-2]
                const int idx = tid - 384, o = idx & 31, ks = idx >> 5;
                const float* hv2 = &sm.hs1[cur][ks * 16];
                const float* wv = &sm.fcw[o * 129 + ks * 16];
                float ssum = 0.f;
                #pragma unroll
                for (int i2 = 0; i2 < 16; ++i2) ssum = fmaf(hv2[i2], wv[i2], ssum);
                sm.pfc[o * 9 + ks] = ssum;
            }
        } else if (tid >= 640) {
            if ((s & (CHX - 1)) == 7 && s + CHX - 7 < TT) {   // write prefetched chunk
                const int i = tid - 640;
                const int buf = ((s >> 4) & 1) ^ 1;
                ((h2*)&sm.xh[buf][0][0])[2*i]   = cvt2(pf.x, pf.y);
                ((h2*)&sm.xh[buf][0][0])[2*i+1] = cvt2(pf.z, pf.w);
            }
        }
        __syncthreads();
        cur = nxt;
    }
}

extern "C" void kernel_launch(void* const* d_in, const int* in_sizes, int n_in,
                              void* d_out, int out_size, void* d_ws, size_t ws_size,
                              hipStream_t stream) {
    const float* x     = (const float*)d_in[0];
    const float* W_ih0 = (const float*)d_in[1];
    const float* W_hh0 = (const float*)d_in[2];
    const float* b_ih0 = (const float*)d_in[3];
    const float* b_hh0 = (const float*)d_in[4];
    const float* W_ih1 = (const float*)d_in[5];
    const float* W_hh1 = (const float*)d_in[6];
    const float* b_ih1 = (const float*)d_in[7];
    const float* b_hh1 = (const float*)d_in[8];
    const float* fc_w  = (const float*)d_in[9];
    const float* fc_b  = (const float*)d_in[10];

    float* out    = (float*)d_out;                 // [B,T,32]
    float* hstack = out + (size_t)BB * TT * NOUT;  // [2,B,128]

    gru_fused_kernel<<<BB, 768, 0, stream>>>(
        x, W_ih0, W_hh0, b_ih0, b_hh0,
        W_ih1, W_hh1, b_ih1, b_hh1,
        fc_w, fc_b, out, hstack);
}